// Round 1
// baseline (371.652 us; speedup 1.0000x reference)
//
#include <hip/hip_runtime.h>
#include <math.h>

// softIoULoss: out = 1 - (I + 1) / (M + (nc+1)*S - I + 1)
//   I = sum(sigmoid(0.5 - |x-t|) * matched)
//   M = sum(matched),  S = sum(sigmoid(0.5 - |x-t|))
//   matched = (t == floor(t)) && (t >= 0) && (t <= nc)
//
// ws layout: [0..2] float accumulators (I, M, S), [3] uint32 block counter.
// Zeroed via hipMemsetAsync each launch (harness re-poisons ws to 0xAA).

__global__ __launch_bounds__(256) void soft_iou_kernel(
    const float* __restrict__ x,
    const float* __restrict__ t,
    const int* __restrict__ ncls_p,
    float* __restrict__ out,
    float* __restrict__ ws_f,
    unsigned int* __restrict__ ws_cnt,
    int n)
{
    const int tid = threadIdx.x;
    const long long gsize = (long long)gridDim.x * blockDim.x;
    const long long gtid  = (long long)blockIdx.x * blockDim.x + tid;

    const float ncf = (float)(*ncls_p);

    float s_inter = 0.f, s_match = 0.f, s_sig = 0.f;

    const long long nvec = n >> 2;              // float4 count
    const float4* x4 = (const float4*)x;
    const float4* t4 = (const float4*)t;

    for (long long i = gtid; i < nvec; i += gsize) {
        float4 xv = x4[i];
        float4 tv = t4[i];
        float xs[4] = {xv.x, xv.y, xv.z, xv.w};
        float ts[4] = {tv.x, tv.y, tv.z, tv.w};
#pragma unroll
        for (int j = 0; j < 4; ++j) {
            float tt = ts[j];
            float z  = 0.5f - fabsf(xs[j] - tt);
            float sg = __builtin_amdgcn_rcpf(1.0f + __expf(-z));
            float m  = (tt == floorf(tt) && tt >= 0.f && tt <= ncf) ? 1.f : 0.f;
            s_sig   += sg;
            s_match += m;
            s_inter += sg * m;
        }
    }
    // scalar tail (n % 4)
    for (long long i = (nvec << 2) + gtid; i < n; i += gsize) {
        float tt = t[i];
        float z  = 0.5f - fabsf(x[i] - tt);
        float sg = __builtin_amdgcn_rcpf(1.0f + __expf(-z));
        float m  = (tt == floorf(tt) && tt >= 0.f && tt <= ncf) ? 1.f : 0.f;
        s_sig += sg; s_match += m; s_inter += sg * m;
    }

    // wave (64-lane) reduction
#pragma unroll
    for (int off = 32; off > 0; off >>= 1) {
        s_inter += __shfl_down(s_inter, off, 64);
        s_match += __shfl_down(s_match, off, 64);
        s_sig   += __shfl_down(s_sig,   off, 64);
    }

    __shared__ float sh[3][4];   // 4 waves for block=256
    const int wid = tid >> 6;
    const int lid = tid & 63;
    if (lid == 0) { sh[0][wid] = s_inter; sh[1][wid] = s_match; sh[2][wid] = s_sig; }
    __syncthreads();

    if (tid == 0) {
        float bi = sh[0][0] + sh[0][1] + sh[0][2] + sh[0][3];
        float bm = sh[1][0] + sh[1][1] + sh[1][2] + sh[1][3];
        float bs = sh[2][0] + sh[2][1] + sh[2][2] + sh[2][3];
        atomicAdd(&ws_f[0], bi);
        atomicAdd(&ws_f[1], bm);
        atomicAdd(&ws_f[2], bs);
        __threadfence();
        unsigned prev = atomicAdd(ws_cnt, 1u);
        if (prev == gridDim.x - 1) {
            // last block: all other blocks' adds are globally visible.
            // Read via device-scope atomic RMW (+0) to bypass stale caches.
            float I = atomicAdd(&ws_f[0], 0.f);
            float M = atomicAdd(&ws_f[1], 0.f);
            float S = atomicAdd(&ws_f[2], 0.f);
            float uni = M + (ncf + 1.f) * S - I;
            out[0] = 1.f - (I + 1.f) / (uni + 1.f);
        }
    }
}

extern "C" void kernel_launch(void* const* d_in, const int* in_sizes, int n_in,
                              void* d_out, int out_size, void* d_ws, size_t ws_size,
                              hipStream_t stream) {
    const float* x  = (const float*)d_in[0];
    const float* t  = (const float*)d_in[1];
    const int*   nc = (const int*)d_in[2];
    float* out = (float*)d_out;
    float* ws_f = (float*)d_ws;
    unsigned int* ws_cnt = (unsigned int*)((char*)d_ws + 12);
    const int n = in_sizes[0];

    hipMemsetAsync(d_ws, 0, 16, stream);

    const int block = 256;
    const int grid  = 2048;   // 16 float4-iters/thread at n=2^25
    soft_iou_kernel<<<grid, block, 0, stream>>>(x, t, nc, out, ws_f, ws_cnt, n);
}